// Round 1
// baseline (225.886 us; speedup 1.0000x reference)
//
#include <hip/hip_runtime.h>
#include <math.h>

#define BB 1024
#define S 32
#define DIM 64
#define NREL 237
#define SIGMA 0.1f

// ---- workspace layout (float offsets) ----
#define OFS_WR    0                       // 238*64  : Wr = relf_ext @ W_agg0 (row 237 = 0)
#define N_WR      (238*64)
#define OFS_OVEC  (OFS_WR + N_WR)         // 2048*64 : ovec per (b,side)
#define N_OVEC    (2048*64)
#define OFS_WC0   (OFS_OVEC + N_OVEC)     // 64*237  : W_agg1 @ W_out[:237]
#define N_WC      (64*237)
#define OFS_WC1   (OFS_WC0 + N_WC)        // 64*237  : W_agg1 @ W_out[237:]
#define OFS_M1    (OFS_WC1 + N_WC)        // 64*64   : W_agg1 @ mW1[:237]
#define N_M1      (64*64)
#define OFS_BC    (OFS_M1 + N_M1)         // 237     : b_agg1@(Wout_top+Wout_bot)+b_out
#define OFS_HC    (OFS_BC + 237)          // 64      : b_agg1@mW1[:237]+mb1

__device__ __forceinline__ float selu_f(float x) {
    const float alpha = 1.6732632423543772f;
    const float scale = 1.0507009873554805f;
    return scale * (x > 0.f ? x : alpha * expm1f(x));
}

// ---------- Kernel A: fold all the linear algebra that doesn't depend on b ----------
__global__ __launch_bounds__(256) void precompute_kernel(
    const float* __restrict__ rel_feat, const float* __restrict__ W0,
    const float* __restrict__ W1, const float* __restrict__ b1,
    const float* __restrict__ W_out, const float* __restrict__ b_out,
    const float* __restrict__ mW1, const float* __restrict__ mb1,
    float* __restrict__ ws) {
    int idx = blockIdx.x * 256 + threadIdx.x;
    const int nWr = 238 * 64, nWc = 64 * 237, nM1 = 64 * 64;
    if (idx < nWr) {                       // Wr[r][o]
        int r = idx >> 6, o = idx & 63;
        float acc = 0.f;
        if (r < NREL)
            for (int d = 0; d < 64; ++d) acc += rel_feat[r * 64 + d] * W0[d * 64 + o];
        ws[OFS_WR + idx] = acc;            // row 237 -> 0 (zero padding row)
        return;
    }
    idx -= nWr;
    if (idx < nWc) {                       // Wc0[o][c]
        int o = idx / 237, c = idx % 237;
        float acc = 0.f;
        for (int k = 0; k < NREL; ++k) acc += W1[o * 237 + k] * W_out[k * 237 + c];
        ws[OFS_WC0 + idx] = acc;
        return;
    }
    idx -= nWc;
    if (idx < nWc) {                       // Wc1[o][c]
        int o = idx / 237, c = idx % 237;
        float acc = 0.f;
        for (int k = 0; k < NREL; ++k) acc += W1[o * 237 + k] * W_out[(237 + k) * 237 + c];
        ws[OFS_WC1 + idx] = acc;
        return;
    }
    idx -= nWc;
    if (idx < nM1) {                       // M1[o][w]
        int o = idx >> 6, w = idx & 63;
        float acc = 0.f;
        for (int k = 0; k < NREL; ++k) acc += W1[o * 237 + k] * mW1[k * 64 + w];
        ws[OFS_M1 + idx] = acc;
        return;
    }
    idx -= nM1;
    if (idx < NREL) {                      // bc[c]
        int c = idx;
        float acc = b_out[c];
        for (int k = 0; k < NREL; ++k)
            acc += b1[k] * (W_out[k * 237 + c] + W_out[(237 + k) * 237 + c]);
        ws[OFS_BC + c] = acc;
        return;
    }
    idx -= NREL;
    if (idx < 64) {                        // hconst[w]
        int w = idx;
        float acc = mb1[w];
        for (int k = 0; k < NREL; ++k) acc += b1[k] * mW1[k * 64 + w];
        ws[OFS_HC + w] = acc;
    }
}

// ---------- Kernel 1: gather + aggregate -> ovec[b][side][64] ----------
// one block per b; both sides sequentially. Mask folded into index (row 237 of Wr is 0).
__global__ __launch_bounds__(256) void gather_kernel(
    const int* __restrict__ ep, const int* __restrict__ te_arr,
    const int* __restrict__ e2e_tab, const int* __restrict__ e2ent,
    const int* __restrict__ e2r, const float* __restrict__ b0,
    float* __restrict__ ws) {
    __shared__ int   s_r2m[1024];
    __shared__ int   s_r1[32];
    __shared__ int   s_ent2[32];
    __shared__ float s_m1[32];
    __shared__ float s_v1[32 * 68];        // padded stride 68 floats

    const int tid = threadIdx.x;
    const int b = blockIdx.x;
    const int te = te_arr[b];
    const int g = tid >> 4;                // 16 groups of 16 threads
    const int c = tid & 15;                // float4 slot within a 64-float row
    const float4* gWr4 = (const float4*)(ws + OFS_WR);
    const float4 b0v = ((const float4*)b0)[c];

    for (int side = 0; side < 2; ++side) {
        if (tid < 32) {
            int ent = ep[b * 2 + side];
            int e1 = e2e_tab[ent * S + tid];
            s_r1[tid] = e2r[e1];
            s_m1[tid] = (e1 != te) ? 1.0f : 0.0f;
            s_ent2[tid] = e2ent[e1];
        }
        __syncthreads();
        for (int p = tid; p < 1024; p += 256) {
            int j = p >> 5, s = p & 31;
            int e2 = e2e_tab[s_ent2[j] * S + s];
            s_r2m[p] = (e2 == te) ? NREL : e2r[e2];   // masked -> zero row
        }
        __syncthreads();
        for (int jj = g; jj < 32; jj += 16) {
            float4 acc = gWr4[s_r1[jj] * 16 + c];     // self term (unmasked)
            float4 sum = make_float4(0.f, 0.f, 0.f, 0.f);
            const int* rr = &s_r2m[jj * 32];
#pragma unroll
            for (int s = 0; s < 32; ++s) {
                float4 v = gWr4[rr[s] * 16 + c];
                sum.x += v.x; sum.y += v.y; sum.z += v.z; sum.w += v.w;
            }
            const float inv = 1.0f / 32.0f;
            float m = s_m1[jj];
            float4 r;
            r.x = fmaxf(acc.x + sum.x * inv + b0v.x, 0.f) * m;
            r.y = fmaxf(acc.y + sum.y * inv + b0v.y, 0.f) * m;
            r.z = fmaxf(acc.z + sum.z * inv + b0v.z, 0.f) * m;
            r.w = fmaxf(acc.w + sum.w * inv + b0v.w, 0.f) * m;
            *((float4*)&s_v1[jj * 68 + c * 4]) = r;
        }
        __syncthreads();
        if (tid < 64) {
            float sum = 0.f;
            for (int j = 0; j < 32; ++j) sum += s_v1[j * 68 + tid];
            ws[OFS_OVEC + (b * 2 + side) * 64 + tid] = sum * (1.0f / 32.0f);
        }
        __syncthreads();
    }
}

// ---------- Kernel 2: per-b epilogue (output GEMVs + SELU MLP + product) ----------
// one wave (64 lanes) per b; 4 waves per block.
__global__ __launch_bounds__(256) void final_kernel(
    const float* __restrict__ t_arr, const float* __restrict__ eps,
    const float* __restrict__ mW1, const float* __restrict__ mW2,
    const float* __restrict__ mb2, const float* __restrict__ mW3,
    const float* __restrict__ mb3, const float* __restrict__ mW4,
    const float* __restrict__ mb4, const float* __restrict__ ws,
    float* __restrict__ out) {
    const int lane = threadIdx.x & 63;
    const int b = blockIdx.x * 4 + (threadIdx.x >> 6);
    const float* ovec = ws + OFS_OVEC;
    const float* Wc0 = ws + OFS_WC0;
    const float* Wc1 = ws + OFS_WC1;
    const float* M1 = ws + OFS_M1;
    const float* bc = ws + OFS_BC;
    const float* hc = ws + OFS_HC;

    float o0 = ovec[(b * 2 + 0) * 64 + lane];
    float o1 = ovec[(b * 2 + 1) * 64 + lane];
    float tb = t_arr[b];
    float omix = (1.f - tb) * o0 + tb * o1;

    const int c0 = lane, c1 = 64 + lane, c2 = 128 + lane, c3 = 192 + lane;
    float out0 = bc[c0], out1 = bc[c1], out2 = bc[c2];
    float out3 = (c3 < NREL) ? bc[c3] : 0.f;
    for (int d = 0; d < 64; ++d) {
        float a0 = __shfl(o0, d);
        float a1 = __shfl(o1, d);
        const float* r0 = Wc0 + d * 237;
        const float* r1p = Wc1 + d * 237;
        out0 += a0 * r0[c0] + a1 * r1p[c0];
        out1 += a0 * r0[c1] + a1 * r1p[c1];
        out2 += a0 * r0[c2] + a1 * r1p[c2];
        if (c3 < NREL) out3 += a0 * r0[c3] + a1 * r1p[c3];
    }

    // h1 = selu(omix@M1 + 0.1*eps@mW1[:237] + t*mW1[237] + hconst)
    float h = hc[lane] + tb * mW1[237 * 64 + lane];
    for (int d = 0; d < 64; ++d) h += __shfl(omix, d) * M1[d * 64 + lane];
    const float* epsb = eps + b * 237;
    for (int k = 0; k < NREL; ++k) h += (SIGMA * epsb[k]) * mW1[k * 64 + lane];
    h = selu_f(h);

    float h2 = mb2[lane];
    for (int d = 0; d < 64; ++d) h2 += __shfl(h, d) * mW2[d * 64 + lane];
    h2 = selu_f(h2);

    float h3 = mb3[lane];
    for (int d = 0; d < 64; ++d) h3 += __shfl(h2, d) * mW3[d * 64 + lane];
    h3 = selu_f(h3);

    float v0 = mb4[c0], v1 = mb4[c1], v2 = mb4[c2];
    float v3 = (c3 < NREL) ? mb4[c3] : 0.f;
    for (int w = 0; w < 64; ++w) {
        float hh = __shfl(h3, w);
        v0 += hh * mW4[w * 237 + c0];
        v1 += hh * mW4[w * 237 + c1];
        v2 += hh * mW4[w * 237 + c2];
        if (c3 < NREL) v3 += hh * mW4[w * 237 + c3];
    }
    float* ob = out + b * 237;
    ob[c0] = out0 * v0;
    ob[c1] = out1 * v1;
    ob[c2] = out2 * v2;
    if (c3 < NREL) ob[c3] = out3 * v3;
}

extern "C" void kernel_launch(void* const* d_in, const int* in_sizes, int n_in,
                              void* d_out, int out_size, void* d_ws, size_t ws_size,
                              hipStream_t stream) {
    const int* ep       = (const int*)d_in[0];
    const int* te       = (const int*)d_in[1];
    // d_in[2] = labels : dead code in the reference (layer-0/hop-0 output is discarded)
    const int* e2e      = (const int*)d_in[3];
    const int* e2ent    = (const int*)d_in[4];
    const int* e2r      = (const int*)d_in[5];
    const float* t      = (const float*)d_in[6];
    const float* eps    = (const float*)d_in[7];
    const float* relf   = (const float*)d_in[8];
    const float* W0     = (const float*)d_in[9];
    const float* b0     = (const float*)d_in[10];
    const float* W1     = (const float*)d_in[11];
    const float* b1     = (const float*)d_in[12];
    const float* W_out  = (const float*)d_in[13];
    const float* b_out  = (const float*)d_in[14];
    const float* mW1    = (const float*)d_in[15];
    const float* mb1    = (const float*)d_in[16];
    const float* mW2    = (const float*)d_in[17];
    const float* mb2    = (const float*)d_in[18];
    const float* mW3    = (const float*)d_in[19];
    const float* mb3    = (const float*)d_in[20];
    const float* mW4    = (const float*)d_in[21];
    const float* mb4    = (const float*)d_in[22];
    float* ws  = (float*)d_ws;
    float* out = (float*)d_out;

    hipLaunchKernelGGL(precompute_kernel, dim3(196), dim3(256), 0, stream,
                       relf, W0, W1, b1, W_out, b_out, mW1, mb1, ws);
    hipLaunchKernelGGL(gather_kernel, dim3(BB), dim3(256), 0, stream,
                       ep, te, e2e, e2ent, e2r, b0, ws);
    hipLaunchKernelGGL(final_kernel, dim3(BB / 4), dim3(256), 0, stream,
                       t, eps, mW1, mW2, mb2, mW3, mb3, mW4, mb4, ws, out);
}

// Round 2
// 173.397 us; speedup vs baseline: 1.3027x; 1.3027x over previous
//
#include <hip/hip_runtime.h>
#include <math.h>

#define BB 1024
#define S 32
#define DIM 64
#define NREL 237
#define SIGMA 0.1f

// ---- workspace layout (float offsets) ----
#define OFS_WR    0                       // 238*64  : Wr = relf_ext @ W_agg0 (row 237 = 0)
#define N_WR      (238*64)
#define OFS_OVEC  (OFS_WR + N_WR)         // 2048*64 : ovec per (b,side)
#define N_OVEC    (2048*64)
#define OFS_WC0   (OFS_OVEC + N_OVEC)     // 64*237  : W_agg1 @ W_out[:237]
#define N_WC      (64*237)
#define OFS_WC1   (OFS_WC0 + N_WC)        // 64*237  : W_agg1 @ W_out[237:]
#define OFS_M1    (OFS_WC1 + N_WC)        // 64*64   : W_agg1 @ mW1[:237]
#define N_M1      (64*64)
#define OFS_BC    (OFS_M1 + N_M1)         // 237     : b_agg1@(Wout_top+Wout_bot)+b_out
#define OFS_HC    (OFS_BC + 237)          // 64      : b_agg1@mW1[:237]+mb1

__device__ __forceinline__ float selu_f(float x) {
    const float alpha = 1.6732632423543772f;
    const float scale = 1.0507009873554805f;
    return scale * (x > 0.f ? x : alpha * expm1f(x));
}

// ---------- Kernel A: fold all b-independent linear algebra ----------
// k-split (4 groups of ~60) + LDS reduce; 641 blocks. Chains 237 -> 60.
__global__ __launch_bounds__(256) void precompute_kernel(
    const float* __restrict__ rel_feat, const float* __restrict__ W0,
    const float* __restrict__ W1, const float* __restrict__ b1,
    const float* __restrict__ W_out, const float* __restrict__ b_out,
    const float* __restrict__ mW1, const float* __restrict__ mb1,
    float* __restrict__ ws) {
    __shared__ float red[256];
    int blk = blockIdx.x;
    const int tid = threadIdx.x;

    if (blk < 60) {                        // Wr[r][o], 64-deep
        int idx = blk * 256 + tid;
        if (idx < 238 * 64) {
            int r = idx >> 6, o = idx & 63;
            float acc = 0.f;
            if (r < NREL) {
#pragma unroll 8
                for (int d = 0; d < 64; ++d)
                    acc += rel_feat[r * 64 + d] * W0[d * 64 + o];
            }
            ws[OFS_WR + idx] = acc;        // row 237 stays 0
        }
        return;
    }
    blk -= 60;
    if (blk < 512) {                       // Wc0 / Wc1 : 64x237 each, 237-deep
        int half = blk >> 8;
        int lb = blk & 255;
        int o = lb >> 2, ct = lb & 3;
        int cl = tid & 63, g = tid >> 6;
        int c = ct * 64 + cl;
        const float* Wsrc = W_out + half * 237 * 237;
        float acc = 0.f;
        if (c < NREL) {
            int k0 = g * 60, k1 = (g == 3) ? 237 : (k0 + 60);
            for (int k = k0; k < k1; ++k)
                acc += W1[o * 237 + k] * Wsrc[k * 237 + c];
        }
        red[tid] = acc;
        __syncthreads();
        if (g == 0 && c < NREL) {
            float s = red[cl] + red[64 + cl] + red[128 + cl] + red[192 + cl];
            ws[(half ? OFS_WC1 : OFS_WC0) + o * 237 + c] = s;
        }
        return;
    }
    blk -= 512;
    if (blk < 64) {                        // M1[o][w], 237-deep
        int o = blk;
        int w = tid & 63, g = tid >> 6;
        int k0 = g * 60, k1 = (g == 3) ? 237 : (k0 + 60);
        float acc = 0.f;
        for (int k = k0; k < k1; ++k)
            acc += W1[o * 237 + k] * mW1[k * 64 + w];
        red[tid] = acc;
        __syncthreads();
        if (g == 0)
            ws[OFS_M1 + o * 64 + w] = red[w] + red[64 + w] + red[128 + w] + red[192 + w];
        return;
    }
    blk -= 64;
    if (blk < 4) {                         // bc[c]
        int cl = tid & 63, g = tid >> 6;
        int c = blk * 64 + cl;
        float acc = 0.f;
        if (c < NREL) {
            int k0 = g * 60, k1 = (g == 3) ? 237 : (k0 + 60);
            for (int k = k0; k < k1; ++k)
                acc += b1[k] * (W_out[k * 237 + c] + W_out[(237 + k) * 237 + c]);
        }
        red[tid] = acc;
        __syncthreads();
        if (g == 0 && c < NREL)
            ws[OFS_BC + c] = b_out[c] + red[cl] + red[64 + cl] + red[128 + cl] + red[192 + cl];
        return;
    }
    // hc[w]
    {
        int w = tid & 63, g = tid >> 6;
        int k0 = g * 60, k1 = (g == 3) ? 237 : (k0 + 60);
        float acc = 0.f;
        for (int k = k0; k < k1; ++k)
            acc += b1[k] * mW1[k * 64 + w];
        red[tid] = acc;
        __syncthreads();
        if (g == 0)
            ws[OFS_HC + w] = mb1[w] + red[w] + red[64 + w] + red[128 + w] + red[192 + w];
    }
}

// ---------- Kernel 1: gather + aggregate -> ovec[b][side][64] ----------
// Wr (61 KB) staged in LDS once per block; all row gathers hit LDS.
// Dynamic LDS: 74112 B -> 2 blocks/CU.
__global__ __launch_bounds__(256) void gather_kernel(
    const int* __restrict__ ep, const int* __restrict__ te_arr,
    const int* __restrict__ e2e_tab, const int* __restrict__ e2ent,
    const int* __restrict__ e2r, const float* __restrict__ b0,
    float* __restrict__ ws) {
    extern __shared__ float smem[];
    float* s_wr   = smem;                        // 238*64 = 15232 floats
    int*   s_r2m  = (int*)(smem + 15232);        // 1024
    int*   s_r1   = (int*)(smem + 16256);        // 32
    int*   s_ent2 = (int*)(smem + 16288);        // 32
    float* s_m1   = smem + 16320;                // 32
    float* s_v1   = smem + 16352;                // 32*68 = 2176 -> total 18528 floats

    const int tid = threadIdx.x;
    const int b = blockIdx.x;
    const int te = te_arr[b];
    const int g = tid >> 4;                // 16 groups of 16 threads
    const int c = tid & 15;                // float4 slot within a 64-float row
    const float4 b0v = ((const float4*)b0)[c];

    // stage Wr into LDS (3808 float4s)
    {
        const float4* src = (const float4*)(ws + OFS_WR);
        float4* dst = (float4*)s_wr;
        for (int i = tid; i < 238 * 16; i += 256) dst[i] = src[i];
    }
    const float4* sWr4 = (const float4*)s_wr;

    for (int side = 0; side < 2; ++side) {
        if (tid < 32) {
            int ent = ep[b * 2 + side];
            int e1 = e2e_tab[ent * S + tid];
            s_r1[tid] = e2r[e1];
            s_m1[tid] = (e1 != te) ? 1.0f : 0.0f;
            s_ent2[tid] = e2ent[e1];
        }
        __syncthreads();                   // also covers the Wr staging on side 0
        for (int p = tid; p < 1024; p += 256) {
            int j = p >> 5, s = p & 31;
            int e2 = e2e_tab[s_ent2[j] * S + s];
            s_r2m[p] = (e2 == te) ? NREL : e2r[e2];   // masked -> zero row
        }
        __syncthreads();
        for (int jj = g; jj < 32; jj += 16) {
            float4 acc = sWr4[s_r1[jj] * 16 + c];     // self term (unmasked)
            float4 sum = make_float4(0.f, 0.f, 0.f, 0.f);
            const int* rr = &s_r2m[jj * 32];
#pragma unroll
            for (int s = 0; s < 32; ++s) {
                float4 v = sWr4[rr[s] * 16 + c];
                sum.x += v.x; sum.y += v.y; sum.z += v.z; sum.w += v.w;
            }
            const float inv = 1.0f / 32.0f;
            float m = s_m1[jj];
            float4 r;
            r.x = fmaxf(acc.x + sum.x * inv + b0v.x, 0.f) * m;
            r.y = fmaxf(acc.y + sum.y * inv + b0v.y, 0.f) * m;
            r.z = fmaxf(acc.z + sum.z * inv + b0v.z, 0.f) * m;
            r.w = fmaxf(acc.w + sum.w * inv + b0v.w, 0.f) * m;
            *((float4*)&s_v1[jj * 68 + c * 4]) = r;
        }
        __syncthreads();
        if (tid < 64) {
            float sum = 0.f;
#pragma unroll 8
            for (int j = 0; j < 32; ++j) sum += s_v1[j * 68 + tid];
            ws[OFS_OVEC + (b * 2 + side) * 64 + tid] = sum * (1.0f / 32.0f);
        }
        __syncthreads();
    }
}

// ---------- Kernel 2: per-b epilogue, one block (256 thr) per b ----------
__global__ __launch_bounds__(256) void final_kernel(
    const float* __restrict__ t_arr, const float* __restrict__ eps,
    const float* __restrict__ mW1, const float* __restrict__ mW2,
    const float* __restrict__ mb2, const float* __restrict__ mW3,
    const float* __restrict__ mb3, const float* __restrict__ mW4,
    const float* __restrict__ mb4, const float* __restrict__ ws,
    float* __restrict__ out) {
    __shared__ float s_o0[64], s_o1[64], s_omix[64];
    __shared__ float s_out[240];
    __shared__ float s_red[256];
    __shared__ float s_ha[64], s_hb[64];

    const int tid = threadIdx.x;
    const int b = blockIdx.x;
    const float* ovec = ws + OFS_OVEC;
    const float* Wc0 = ws + OFS_WC0;
    const float* Wc1 = ws + OFS_WC1;
    const float* M1 = ws + OFS_M1;
    const float* bc = ws + OFS_BC;
    const float* hc = ws + OFS_HC;
    const float tb = t_arr[b];

    if (tid < 64) {
        float o0 = ovec[(b * 2 + 0) * 64 + tid];
        float o1 = ovec[(b * 2 + 1) * 64 + tid];
        s_o0[tid] = o0; s_o1[tid] = o1;
        s_omix[tid] = (1.f - tb) * o0 + tb * o1;
    }
    __syncthreads();

    // out[c] = bc[c] + o0 @ Wc0[:,c] + o1 @ Wc1[:,c]   (thread c owns column c)
    if (tid < NREL) {
        float acc = bc[tid];
#pragma unroll 4
        for (int d = 0; d < 64; ++d)
            acc += s_o0[d] * Wc0[d * 237 + tid] + s_o1[d] * Wc1[d * 237 + tid];
        s_out[tid] = acc;
    }

    // h1 partials: (w = tid&63, g = tid>>6); eps-term k-split + M1-term d-split
    {
        int w = tid & 63, gg = tid >> 6;
        float acc = 0.f;
        int k0 = gg * 60, k1 = (gg == 3) ? 237 : (k0 + 60);
        const float* epsb = eps + b * 237;
        for (int k = k0; k < k1; ++k)
            acc += epsb[k] * mW1[k * 64 + w];
        acc *= SIGMA;
#pragma unroll
        for (int d = gg * 16; d < gg * 16 + 16; ++d)
            acc += s_omix[d] * M1[d * 64 + w];
        s_red[tid] = acc;
    }
    __syncthreads();
    if (tid < 64) {
        float h = hc[tid] + tb * mW1[237 * 64 + tid]
                + s_red[tid] + s_red[64 + tid] + s_red[128 + tid] + s_red[192 + tid];
        s_ha[tid] = selu_f(h);
    }
    __syncthreads();

    // h2
    {
        int w = tid & 63, gg = tid >> 6;
        float acc = 0.f;
#pragma unroll
        for (int d = gg * 16; d < gg * 16 + 16; ++d)
            acc += s_ha[d] * mW2[d * 64 + w];
        s_red[tid] = acc;
    }
    __syncthreads();
    if (tid < 64)
        s_hb[tid] = selu_f(mb2[tid] + s_red[tid] + s_red[64 + tid] + s_red[128 + tid] + s_red[192 + tid]);
    __syncthreads();

    // h3
    {
        int w = tid & 63, gg = tid >> 6;
        float acc = 0.f;
#pragma unroll
        for (int d = gg * 16; d < gg * 16 + 16; ++d)
            acc += s_hb[d] * mW3[d * 64 + w];
        s_red[tid] = acc;
    }
    __syncthreads();
    if (tid < 64)
        s_ha[tid] = selu_f(mb3[tid] + s_red[tid] + s_red[64 + tid] + s_red[128 + tid] + s_red[192 + tid]);
    __syncthreads();

    // vt[c] and final product
    if (tid < NREL) {
        float acc = mb4[tid];
#pragma unroll 4
        for (int w = 0; w < 64; ++w)
            acc += s_ha[w] * mW4[w * 237 + tid];
        out[b * 237 + tid] = s_out[tid] * acc;
    }
}

extern "C" void kernel_launch(void* const* d_in, const int* in_sizes, int n_in,
                              void* d_out, int out_size, void* d_ws, size_t ws_size,
                              hipStream_t stream) {
    const int* ep       = (const int*)d_in[0];
    const int* te       = (const int*)d_in[1];
    // d_in[2] = labels : dead code in the reference
    const int* e2e      = (const int*)d_in[3];
    const int* e2ent    = (const int*)d_in[4];
    const int* e2r      = (const int*)d_in[5];
    const float* t      = (const float*)d_in[6];
    const float* eps    = (const float*)d_in[7];
    const float* relf   = (const float*)d_in[8];
    const float* W0     = (const float*)d_in[9];
    const float* b0     = (const float*)d_in[10];
    const float* W1     = (const float*)d_in[11];
    const float* b1     = (const float*)d_in[12];
    const float* W_out  = (const float*)d_in[13];
    const float* b_out  = (const float*)d_in[14];
    const float* mW1    = (const float*)d_in[15];
    const float* mb1    = (const float*)d_in[16];
    const float* mW2    = (const float*)d_in[17];
    const float* mb2    = (const float*)d_in[18];
    const float* mW3    = (const float*)d_in[19];
    const float* mb3    = (const float*)d_in[20];
    const float* mW4    = (const float*)d_in[21];
    const float* mb4    = (const float*)d_in[22];
    float* ws  = (float*)d_ws;
    float* out = (float*)d_out;

    hipLaunchKernelGGL(precompute_kernel, dim3(641), dim3(256), 0, stream,
                       relf, W0, W1, b1, W_out, b_out, mW1, mb1, ws);
    hipLaunchKernelGGL(gather_kernel, dim3(BB), dim3(256), 74112, stream,
                       ep, te, e2e, e2ent, e2r, b0, ws);
    hipLaunchKernelGGL(final_kernel, dim3(BB), dim3(256), 0, stream,
                       t, eps, mW1, mW2, mb2, mW3, mb3, mW4, mb4, ws, out);
}

// Round 3
// 154.793 us; speedup vs baseline: 1.4593x; 1.1202x over previous
//
#include <hip/hip_runtime.h>
#include <math.h>

#define BB 1024
#define S 32
#define DIM 64
#define NREL 237
#define SIGMA 0.1f

// ---- workspace layout (float offsets) ----
#define OFS_WR    0                       // 238*64  : Wr = relf_ext @ W_agg0 (row 237 = 0)
#define N_WR      (238*64)
#define OFS_OVEC  (OFS_WR + N_WR)         // 2048*64 : ovec per (b,side)
#define N_OVEC    (2048*64)
#define OFS_WC0   (OFS_OVEC + N_OVEC)     // 64*237  : W_agg1 @ W_out[:237]
#define N_WC      (64*237)
#define OFS_WC1   (OFS_WC0 + N_WC)        // 64*237  : W_agg1 @ W_out[237:]
#define OFS_M1    (OFS_WC1 + N_WC)        // 64*64   : W_agg1 @ mW1[:237]
#define N_M1      (64*64)
#define OFS_BC    (OFS_M1 + N_M1)         // 237
#define OFS_HC    (OFS_BC + 237)          // 64

__device__ __forceinline__ float selu_f(float x) {
    const float alpha = 1.6732632423543772f;
    const float scale = 1.0507009873554805f;
    return scale * (x > 0.f ? x : alpha * expm1f(x));
}

// ---------- Kernel A: fold all b-independent linear algebra ----------
__global__ __launch_bounds__(256) void precompute_kernel(
    const float* __restrict__ rel_feat, const float* __restrict__ W0,
    const float* __restrict__ W1, const float* __restrict__ b1,
    const float* __restrict__ W_out, const float* __restrict__ b_out,
    const float* __restrict__ mW1, const float* __restrict__ mb1,
    float* __restrict__ ws) {
    __shared__ float red[256];
    int blk = blockIdx.x;
    const int tid = threadIdx.x;

    if (blk < 60) {                        // Wr[r][o], 64-deep
        int idx = blk * 256 + tid;
        if (idx < 238 * 64) {
            int r = idx >> 6, o = idx & 63;
            float acc = 0.f;
            if (r < NREL) {
#pragma unroll 8
                for (int d = 0; d < 64; ++d)
                    acc += rel_feat[r * 64 + d] * W0[d * 64 + o];
            }
            ws[OFS_WR + idx] = acc;        // row 237 stays 0
        }
        return;
    }
    blk -= 60;
    if (blk < 512) {                       // Wc0 / Wc1 : 64x237 each, 237-deep
        int half = blk >> 8;
        int lb = blk & 255;
        int o = lb >> 2, ct = lb & 3;
        int cl = tid & 63, g = tid >> 6;
        int c = ct * 64 + cl;
        const float* Wsrc = W_out + half * 237 * 237;
        float acc = 0.f;
        if (c < NREL) {
            int k0 = g * 60, k1 = (g == 3) ? 237 : (k0 + 60);
#pragma unroll 4
            for (int k = k0; k < k1; ++k)
                acc += W1[o * 237 + k] * Wsrc[k * 237 + c];
        }
        red[tid] = acc;
        __syncthreads();
        if (g == 0 && c < NREL) {
            float s = red[cl] + red[64 + cl] + red[128 + cl] + red[192 + cl];
            ws[(half ? OFS_WC1 : OFS_WC0) + o * 237 + c] = s;
        }
        return;
    }
    blk -= 512;
    if (blk < 64) {                        // M1[o][w], 237-deep
        int o = blk;
        int w = tid & 63, g = tid >> 6;
        int k0 = g * 60, k1 = (g == 3) ? 237 : (k0 + 60);
        float acc = 0.f;
#pragma unroll 4
        for (int k = k0; k < k1; ++k)
            acc += W1[o * 237 + k] * mW1[k * 64 + w];
        red[tid] = acc;
        __syncthreads();
        if (g == 0)
            ws[OFS_M1 + o * 64 + w] = red[w] + red[64 + w] + red[128 + w] + red[192 + w];
        return;
    }
    blk -= 64;
    if (blk < 4) {                         // bc[c]
        int cl = tid & 63, g = tid >> 6;
        int c = blk * 64 + cl;
        float acc = 0.f;
        if (c < NREL) {
            int k0 = g * 60, k1 = (g == 3) ? 237 : (k0 + 60);
#pragma unroll 4
            for (int k = k0; k < k1; ++k)
                acc += b1[k] * (W_out[k * 237 + c] + W_out[(237 + k) * 237 + c]);
        }
        red[tid] = acc;
        __syncthreads();
        if (g == 0 && c < NREL)
            ws[OFS_BC + c] = b_out[c] + red[cl] + red[64 + cl] + red[128 + cl] + red[192 + cl];
        return;
    }
    // hc[w]
    {
        int w = tid & 63, g = tid >> 6;
        int k0 = g * 60, k1 = (g == 3) ? 237 : (k0 + 60);
        float acc = 0.f;
#pragma unroll 4
        for (int k = k0; k < k1; ++k)
            acc += b1[k] * mW1[k * 64 + w];
        red[tid] = acc;
        __syncthreads();
        if (g == 0)
            ws[OFS_HC + w] = mb1[w] + red[w] + red[64 + w] + red[128 + w] + red[192 + w];
    }
}

// ---------- Kernel 1: gather + aggregate -> ovec, 2 b's per block ----------
// 512 blocks x 74KB LDS = 2 blocks/CU -> ALL blocks resident in one round.
// Wr staged once per block, reused across 4 (b,side) units.
__global__ __launch_bounds__(256) void gather_kernel(
    const int* __restrict__ ep, const int* __restrict__ te_arr,
    const int* __restrict__ e2e_tab, const int* __restrict__ e2ent,
    const int* __restrict__ e2r, const float* __restrict__ b0,
    float* __restrict__ ws) {
    extern __shared__ float smem[];
    float* s_wr   = smem;                        // 238*64 = 15232 floats
    int*   s_r2m  = (int*)(smem + 15232);        // 1024
    int*   s_r1   = (int*)(smem + 16256);        // 32
    int*   s_ent2 = (int*)(smem + 16288);        // 32
    float* s_m1   = smem + 16320;                // 32
    float* s_v1   = smem + 16352;                // 32*68

    const int tid = threadIdx.x;
    const int bbase = blockIdx.x * 2;
    const int g = tid >> 4;                // 16 groups of 16 threads
    const int c = tid & 15;
    const float4 b0v = ((const float4*)b0)[c];

    // stage Wr into LDS (3808 float4s)
    {
        const float4* src = (const float4*)(ws + OFS_WR);
        float4* dst = (float4*)s_wr;
        for (int i = tid; i < 238 * 16; i += 256) dst[i] = src[i];
    }
    const float4* sWr4 = (const float4*)s_wr;

    for (int u = 0; u < 4; ++u) {
        const int b = bbase + (u >> 1);
        const int side = u & 1;
        const int te = te_arr[b];
        if (tid < 32) {
            int ent = ep[b * 2 + side];
            int e1 = e2e_tab[ent * S + tid];
            s_r1[tid] = e2r[e1];
            s_m1[tid] = (e1 != te) ? 1.0f : 0.0f;
            s_ent2[tid] = e2ent[e1];
        }
        __syncthreads();                   // covers Wr staging on u==0
        for (int p = tid; p < 1024; p += 256) {
            int j = p >> 5, s = p & 31;
            int e2 = e2e_tab[s_ent2[j] * S + s];
            s_r2m[p] = (e2 == te) ? NREL : e2r[e2];   // masked -> zero row of Wr
        }
        __syncthreads();
        for (int jj = g; jj < 32; jj += 16) {
            float4 acc = sWr4[s_r1[jj] * 16 + c];     // self term (unmasked)
            float4 sa = make_float4(0.f, 0.f, 0.f, 0.f);
            float4 sb = make_float4(0.f, 0.f, 0.f, 0.f);
            const int* rr = &s_r2m[jj * 32];
#pragma unroll
            for (int s = 0; s < 16; ++s) {
                float4 v = sWr4[rr[s] * 16 + c];
                sa.x += v.x; sa.y += v.y; sa.z += v.z; sa.w += v.w;
            }
#pragma unroll
            for (int s = 16; s < 32; ++s) {
                float4 v = sWr4[rr[s] * 16 + c];
                sb.x += v.x; sb.y += v.y; sb.z += v.z; sb.w += v.w;
            }
            const float inv = 1.0f / 32.0f;
            float m = s_m1[jj];
            float4 r;
            r.x = fmaxf(acc.x + (sa.x + sb.x) * inv + b0v.x, 0.f) * m;
            r.y = fmaxf(acc.y + (sa.y + sb.y) * inv + b0v.y, 0.f) * m;
            r.z = fmaxf(acc.z + (sa.z + sb.z) * inv + b0v.z, 0.f) * m;
            r.w = fmaxf(acc.w + (sa.w + sb.w) * inv + b0v.w, 0.f) * m;
            *((float4*)&s_v1[jj * 68 + c * 4]) = r;
        }
        __syncthreads();
        if (tid < 64) {
            float sum = 0.f;
#pragma unroll 8
            for (int j = 0; j < 32; ++j) sum += s_v1[j * 68 + tid];
            ws[OFS_OVEC + (b * 2 + side) * 64 + tid] = sum * (1.0f / 32.0f);
        }
        __syncthreads();
    }
}

// ---------- Kernel 2: epilogue, 2 b's per block (weights loaded once, 2 accs) ----------
__global__ __launch_bounds__(256) void final_kernel(
    const float* __restrict__ t_arr, const float* __restrict__ eps,
    const float* __restrict__ mW1, const float* __restrict__ mW2,
    const float* __restrict__ mb2, const float* __restrict__ mW3,
    const float* __restrict__ mb3, const float* __restrict__ mW4,
    const float* __restrict__ mb4, const float* __restrict__ ws,
    float* __restrict__ out) {
    __shared__ float s_o0[2][64], s_o1[2][64], s_omix[2][64];
    __shared__ float s_out[2][240];
    __shared__ float s_red[2][256];
    __shared__ float s_h[2][64];

    const int tid = threadIdx.x;
    const int bb = blockIdx.x * 2;
    const float* ovec = ws + OFS_OVEC;
    const float* Wc0 = ws + OFS_WC0;
    const float* Wc1 = ws + OFS_WC1;
    const float* M1 = ws + OFS_M1;
    const float* bc = ws + OFS_BC;
    const float* hc = ws + OFS_HC;
    const float tb0 = t_arr[bb];
    const float tb1 = t_arr[bb + 1];

    if (tid < 128) {
        int p = tid >> 6, w = tid & 63;
        float tb = p ? tb1 : tb0;
        float o0 = ovec[((bb + p) * 2 + 0) * 64 + w];
        float o1 = ovec[((bb + p) * 2 + 1) * 64 + w];
        s_o0[p][w] = o0; s_o1[p][w] = o1;
        s_omix[p][w] = (1.f - tb) * o0 + tb * o1;
    }
    __syncthreads();

    // out[c] for both b's; Wc loaded once
    if (tid < NREL) {
        float a0 = bc[tid], a1 = a0;
#pragma unroll 4
        for (int d = 0; d < 64; ++d) {
            float w0 = Wc0[d * 237 + tid];
            float w1 = Wc1[d * 237 + tid];
            a0 += s_o0[0][d] * w0 + s_o1[0][d] * w1;
            a1 += s_o0[1][d] * w0 + s_o1[1][d] * w1;
        }
        s_out[0][tid] = a0;
        s_out[1][tid] = a1;
    }

    // h1 partials: eps-term k-split + M1-term d-split, both b's share weight loads
    {
        int w = tid & 63, gg = tid >> 6;
        float a0 = 0.f, a1 = 0.f;
        int k0 = gg * 60, k1 = (gg == 3) ? 237 : (k0 + 60);
        const float* e0 = eps + bb * 237;
        const float* e1 = eps + (bb + 1) * 237;
#pragma unroll 4
        for (int k = k0; k < k1; ++k) {
            float m = mW1[k * 64 + w];
            a0 += e0[k] * m;
            a1 += e1[k] * m;
        }
        a0 *= SIGMA; a1 *= SIGMA;
#pragma unroll
        for (int d = gg * 16; d < gg * 16 + 16; ++d) {
            float m = M1[d * 64 + w];
            a0 += s_omix[0][d] * m;
            a1 += s_omix[1][d] * m;
        }
        s_red[0][tid] = a0;
        s_red[1][tid] = a1;
    }
    __syncthreads();
    if (tid < 128) {
        int p = tid >> 6, w = tid & 63;
        float tb = p ? tb1 : tb0;
        float h = hc[w] + tb * mW1[237 * 64 + w]
                + s_red[p][w] + s_red[p][64 + w] + s_red[p][128 + w] + s_red[p][192 + w];
        s_h[p][w] = selu_f(h);
    }
    __syncthreads();

    // h2
    {
        int w = tid & 63, gg = tid >> 6;
        float a0 = 0.f, a1 = 0.f;
#pragma unroll
        for (int d = gg * 16; d < gg * 16 + 16; ++d) {
            float m = mW2[d * 64 + w];
            a0 += s_h[0][d] * m;
            a1 += s_h[1][d] * m;
        }
        s_red[0][tid] = a0;
        s_red[1][tid] = a1;
    }
    __syncthreads();
    if (tid < 128) {
        int p = tid >> 6, w = tid & 63;
        s_h[p][w] = 0.f;   // placeholder; real value computed below after reduce
        float v = mb2[w] + s_red[p][w] + s_red[p][64 + w] + s_red[p][128 + w] + s_red[p][192 + w];
        s_h[p][w] = selu_f(v);
    }
    __syncthreads();

    // h3
    {
        int w = tid & 63, gg = tid >> 6;
        float a0 = 0.f, a1 = 0.f;
#pragma unroll
        for (int d = gg * 16; d < gg * 16 + 16; ++d) {
            float m = mW3[d * 64 + w];
            a0 += s_h[0][d] * m;
            a1 += s_h[1][d] * m;
        }
        s_red[0][tid] = a0;
        s_red[1][tid] = a1;
    }
    __syncthreads();
    if (tid < 128) {
        int p = tid >> 6, w = tid & 63;
        float v = mb3[w] + s_red[p][w] + s_red[p][64 + w] + s_red[p][128 + w] + s_red[p][192 + w];
        s_h[p][w] = selu_f(v);
    }
    __syncthreads();

    // vt[c] and final product, both b's
    if (tid < NREL) {
        float a0 = mb4[tid], a1 = a0;
#pragma unroll 4
        for (int w = 0; w < 64; ++w) {
            float m = mW4[w * 237 + tid];
            a0 += s_h[0][w] * m;
            a1 += s_h[1][w] * m;
        }
        out[bb * 237 + tid] = s_out[0][tid] * a0;
        out[(bb + 1) * 237 + tid] = s_out[1][tid] * a1;
    }
}

extern "C" void kernel_launch(void* const* d_in, const int* in_sizes, int n_in,
                              void* d_out, int out_size, void* d_ws, size_t ws_size,
                              hipStream_t stream) {
    const int* ep       = (const int*)d_in[0];
    const int* te       = (const int*)d_in[1];
    // d_in[2] = labels : dead code in the reference
    const int* e2e      = (const int*)d_in[3];
    const int* e2ent    = (const int*)d_in[4];
    const int* e2r      = (const int*)d_in[5];
    const float* t      = (const float*)d_in[6];
    const float* eps    = (const float*)d_in[7];
    const float* relf   = (const float*)d_in[8];
    const float* W0     = (const float*)d_in[9];
    const float* b0     = (const float*)d_in[10];
    const float* W1     = (const float*)d_in[11];
    const float* b1     = (const float*)d_in[12];
    const float* W_out  = (const float*)d_in[13];
    const float* b_out  = (const float*)d_in[14];
    const float* mW1    = (const float*)d_in[15];
    const float* mb1    = (const float*)d_in[16];
    const float* mW2    = (const float*)d_in[17];
    const float* mb2    = (const float*)d_in[18];
    const float* mW3    = (const float*)d_in[19];
    const float* mb3    = (const float*)d_in[20];
    const float* mW4    = (const float*)d_in[21];
    const float* mb4    = (const float*)d_in[22];
    float* ws  = (float*)d_ws;
    float* out = (float*)d_out;

    hipLaunchKernelGGL(precompute_kernel, dim3(641), dim3(256), 0, stream,
                       relf, W0, W1, b1, W_out, b_out, mW1, mb1, ws);
    hipLaunchKernelGGL(gather_kernel, dim3(BB / 2), dim3(256), 74112, stream,
                       ep, te, e2e, e2ent, e2r, b0, ws);
    hipLaunchKernelGGL(final_kernel, dim3(BB / 2), dim3(256), 0, stream,
                       t, eps, mW1, mW2, mb2, mW3, mb3, mW4, mb4, ws, out);
}